// Round 6
// baseline (79.452 us; speedup 1.0000x reference)
//
#include <hip/hip_runtime.h>

#define NB 32768
#define GPB 8
#define THREADS 256
#define BIAS_SP 0.5413248546129181f

typedef __attribute__((ext_vector_type(8))) short bf16x8;
typedef __attribute__((ext_vector_type(4))) float f32x4;
typedef __attribute__((ext_vector_type(4))) unsigned int u32x4;

static __device__ __forceinline__ unsigned f2bfu(float f) {
    union { float f; unsigned u; } v; v.f = f;
    return (v.u + 0x8000u) >> 16;
}
static __device__ __forceinline__ unsigned f2bfu_hi(float f) {
    union { float f; unsigned u; } v; v.f = f;
    return (v.u + 0x8000u) & 0xFFFF0000u;
}
static __device__ __forceinline__ float lof(unsigned u) {
    union { unsigned u; float f; } v; v.u = u << 16; return v.f;
}
static __device__ __forceinline__ float hif(unsigned u) {
    union { unsigned u; float f; } v; v.u = u & 0xFFFF0000u; return v.f;
}
static __device__ __forceinline__ float fast_tanh(float xx) {
    float e = __expf(2.0f * xx);
    return 1.0f - 2.0f * __builtin_amdgcn_rcpf(e + 1.0f);
}

// ---------------------------------------------------------------------------
// Setup: pack conv B-fragments (bf16, MFMA lane order) and head weights
// (bf16 [item=(p-1)*4+j][k=0..63]) into the workspace.
// ws layout (dwords): [0,12288) conv B-frags, [12288,14080) head weights.
// ---------------------------------------------------------------------------
__global__ void setup_kernel(const float* __restrict__ Wroot, const float* __restrict__ Wrel,
                             const float* __restrict__ legW, const float* __restrict__ torW,
                             unsigned* __restrict__ wsw) {
    const int t = blockIdx.x * 256 + threadIdx.x;
    if (t < 3072) {                       // (i,s,ct,lane) B-fragment element pack
        const int i = t >> 10, rem = t & 1023, s = rem >> 8, tt = rem & 255;
        const int lane = tt & 63, ctl = tt >> 6;
        const int bcol = (ctl << 4) + (lane & 15);
        const int kb = ((s & 1) << 5) + ((lane >> 4) << 3);
        const float* M = ((s < 2) ? Wroot : Wrel) + i * 4096 + kb * 64 + bcol;
        u32x4 d;
        #pragma unroll
        for (int dd = 0; dd < 4; ++dd)
            d[dd] = f2bfu(M[(2 * dd) * 64]) | (f2bfu(M[(2 * dd + 1) * 64]) << 16);
        *(u32x4*)(wsw + t * 4) = d;
    } else if (t < 3520) {                // head weights
        const int t2 = t - 3072, item = t2 >> 3, k8 = t2 & 7;
        const int p = (item >> 2) + 1, j = item & 3;
        const int p3 = (p * 11) >> 5;     // p/3 for p<16
        const int pm3 = p - p3 * 3;
        const float* src;
        if (pm3 == 0) src = torW + (p3 - 1) * 256 + j;
        else          src = legW + (2 * p3 + pm3 - 1) * 256 + j;
        u32x4 d;
        #pragma unroll
        for (int dd = 0; dd < 4; ++dd) {
            const int k = (k8 << 3) + 2 * dd;
            d[dd] = f2bfu(src[k * 4]) | (f2bfu(src[(k + 1) * 4]) << 16);
        }
        *(u32x4*)(wsw + 12288 + t2 * 4) = d;
    }
}

// ---------------------------------------------------------------------------
// Main: 8 graphs/block, 4 waves. Conv: wave = col-tile (16 cols), all 8 graphs.
// Enc/AGG/heads: wave owns graphs 2*ct, 2*ct+1.
// LDS/graph: 16 rows x 16 slots(16B) = 4KB; slots 0-7 = h, 8-15 = agg.
// Swizzle: slot_low3 ^= (row & 7) -> row-strided access conflict-free.
// launch_bounds(256,4): 128-VGPR cap. (256,5)'s 48-VGPR allocation caused
// heavy rematerialization (VALU dark matter); 4 blocks x 32KB LDS still fits.
// ---------------------------------------------------------------------------
__global__ __launch_bounds__(THREADS, 4) void leg_main(
    const float* __restrict__ x,
    const float* __restrict__ Wt, const float* __restrict__ bt,
    const float* __restrict__ Wl, const float* __restrict__ bl,
    const float* __restrict__ gcb,
    const float* __restrict__ legB, const float* __restrict__ torB,
    const unsigned* __restrict__ wsw,
    float* __restrict__ out)
{
    __shared__ __align__(16) unsigned char smem[GPB * 4096];
    const int tid  = threadIdx.x;
    const int lane = tid & 63;
    const int ct   = tid >> 6;                 // wave id
    const int g0   = blockIdx.x * GPB;

    const int bcol = (ct << 4) + (lane & 15);
    const float cb0 = gcb[bcol], cb1 = gcb[64 + bcol], cb2 = gcb[128 + bcol];

    // --- per-lane LDS byte offsets (conv) ---
    const int colb = ((lane >> 3) << 4) + ((lane & 7) << 1);   // col = lane (u16)
    const int row = lane & 15, kg = lane >> 4;
    const int row3 = (row * 11) >> 5;
    const int tors = row3 * 3;
    const int isT  = (row == tors);
    const int rowR = isT ? row : tors;         // leg rows read torso h as their agg
    const int voffA0 = row * 256 + (((kg ^ row) & 7) << 4);
    const int voffA2 = rowR * 256 + (((kg ^ rowR) & 7) << 4) + (isT ? 128 : 0);
    int voffC[4];
    #pragma unroll
    for (int r = 0; r < 4; ++r) {
        const int rr = (kg << 2) + r;
        voffC[r] = rr * 256 + (((((ct << 1) + ((lane >> 3) & 1)) ^ rr) & 7) << 4) + ((lane & 7) << 1);
    }

    // --- paired-AGG lane mapping: lanes<32 -> graph 2ct, >=32 -> 2ct+1 ---
    const int half = lane >> 5;
    const int c2   = lane & 31;                // dword index within 64-col row
    unsigned char* gbase = smem + ((ct << 1) + half) * 4096;
    const int aoff = (c2 & 3) << 2;
    // AGG addresses hoisted: computed once, reused across all 3 AGG calls.
    int agg_ra[15];
    #pragma unroll
    for (int r = 0; r < 15; ++r)
        agg_ra[r] = r * 256 + ((((c2 >> 2) ^ r) & 7) << 4) + aoff;
    int agg_wa[5];
    #pragma unroll
    for (int i = 0; i < 5; ++i) {
        const int r = 3 * i;
        agg_wa[i] = r * 256 + 128 + ((((c2 >> 2) ^ r) & 7) << 4) + aoff;
    }
#define RD32(r)  (*(const unsigned*)(gbase + agg_ra[r]))
#define WR32(i, flo, fhi) *(unsigned*)(gbase + agg_wa[i]) = (f2bfu(flo) | f2bfu_hi(fhi))
#define AGG() do { \
    unsigned u[15]; \
    _Pragma("unroll") for (int r = 0; r < 15; ++r) u[r] = RD32(r); \
    float l3 = lof(u[3]), h3 = hif(u[3]), l6 = lof(u[6]), h6 = hif(u[6]), l9 = lof(u[9]), h9 = hif(u[9]); \
    WR32(0,  lof(u[1]) + lof(u[2]) + l3,              hif(u[1]) + hif(u[2]) + h3); \
    WR32(1,  lof(u[4]) + lof(u[5]) + lof(u[0]) + l6,  hif(u[4]) + hif(u[5]) + hif(u[0]) + h6); \
    WR32(2,  lof(u[7]) + lof(u[8]) + l3 + l9,         hif(u[7]) + hif(u[8]) + h3 + h9); \
    WR32(3,  lof(u[10]) + lof(u[11]) + l6 + lof(u[12]), hif(u[10]) + hif(u[11]) + h6 + hif(u[12])); \
    WR32(4,  lof(u[13]) + lof(u[14]) + l9,            hif(u[13]) + hif(u[14]) + h9); \
} while (0)

    // --- encoder: wave ct -> graphs 2ct, 2ct+1 ---
    float ewt[8], ewl[4];
    #pragma unroll
    for (int k = 0; k < 8; ++k) ewt[k] = Wt[(k << 6) + lane];
    #pragma unroll
    for (int k = 0; k < 4; ++k) ewl[k] = Wl[(k << 6) + lane];
    const float ebt = bt[lane], ebl = bl[lane];

    #pragma unroll
    for (int gs = 0; gs < 2; ++gs) {
        const int g = (ct << 1) + gs;
        const float4* xg = (const float4*)(x + (size_t)(g0 + g) * 120);
        unsigned char* sb = smem + g * 4096;
        #pragma unroll
        for (int p = 0; p < 15; ++p) {
            const float4 a0 = xg[p * 2];
            float acc;
            if (p % 3 == 0) {
                const float4 a1 = xg[p * 2 + 1];
                acc = ebt + a0.x * ewt[0] + a0.y * ewt[1] + a0.z * ewt[2] + a0.w * ewt[3]
                          + a1.x * ewt[4] + a1.y * ewt[5] + a1.z * ewt[6] + a1.w * ewt[7];
            } else {
                acc = ebl + a0.x * ewl[0] + a0.y * ewl[1] + a0.z * ewl[2] + a0.w * ewl[3];
            }
            *(unsigned short*)(sb + p * 256 + (colb ^ ((p & 7) << 4))) =
                (unsigned short)f2bfu(fast_tanh(acc));
        }
        *(unsigned short*)(sb + 15 * 256 + (colb ^ 0x70)) = 0;          // pad row h
        *(unsigned short*)(sb + 15 * 256 + 128 + (colb ^ 0x70)) = 0;    // pad row agg
    }
    // Paired AGG reads cols written by OTHER lanes -> barrier required.
    __syncthreads();
    AGG();
    __syncthreads();

    // --- 3x GraphConv via MFMA; wave ct = col-tile for all 8 graphs ---
    #pragma unroll
    for (int it = 0; it < 3; ++it) {
        bf16x8 bfr[4];
        #pragma unroll
        for (int s = 0; s < 4; ++s)
            bfr[s] = *(const bf16x8*)(wsw + ((it * 4 + s) * 256 + tid) * 4);
        const float cbi = (it == 0) ? cb0 : (it == 1) ? cb1 : cb2;
        f32x4 acc[GPB];
        #pragma unroll
        for (int g = 0; g < GPB; ++g) {
            const unsigned char* sg = smem + g * 4096;
            const bf16x8 a0 = *(const bf16x8*)(sg + voffA0);
            const bf16x8 a1 = *(const bf16x8*)(sg + (voffA0 ^ 0x40));
            const bf16x8 a2 = *(const bf16x8*)(sg + voffA2);
            const bf16x8 a3 = *(const bf16x8*)(sg + (voffA2 ^ 0x40));
            f32x4 c = { cbi, cbi, cbi, cbi };
            c = __builtin_amdgcn_mfma_f32_16x16x32_bf16(a0, bfr[0], c, 0, 0, 0);
            c = __builtin_amdgcn_mfma_f32_16x16x32_bf16(a1, bfr[1], c, 0, 0, 0);
            c = __builtin_amdgcn_mfma_f32_16x16x32_bf16(a2, bfr[2], c, 0, 0, 0);
            c = __builtin_amdgcn_mfma_f32_16x16x32_bf16(a3, bfr[3], c, 0, 0, 0);
            acc[g] = c;
        }
        __syncthreads();     // all A reads done before overwriting h
        #pragma unroll
        for (int g = 0; g < GPB; ++g)
            #pragma unroll
            for (int r = 0; r < 4; ++r)
                *(unsigned short*)(smem + g * 4096 + voffC[r]) =
                    (unsigned short)f2bfu(fast_tanh(acc[g][r]));
        __syncthreads();
        if (it < 2) { AGG(); __syncthreads(); }
    }

    // --- heads: wave ct -> graphs 2ct, 2ct+1; lane = (p,j) item ---
    // unpack-FMA path (proven). Raw-asm v_dot2_f32_bf16 gave a deterministic
    // 4.7e-2 error (VOP3P op_sel_hi default) - do not reintroduce via raw asm.
    if (lane < 56) {
        const int p = (lane >> 2) + 1, j = lane & 3;
        const int p3 = (p * 11) >> 5;
        const int pm3 = p - p3 * 3;
        float bias;
        if (pm3 == 0) bias = torB[((p3 - 1) << 2) + j];
        else          bias = legB[(((p3 << 1) + pm3 - 1) << 2) + j];
        const unsigned* wp = wsw + 12288 + (lane << 5);
        const int ps = (p & 7) << 4;
        #pragma unroll
        for (int gs = 0; gs < 2; ++gs) {
            const int g = (ct << 1) + gs;
            const unsigned char* hb = smem + g * 4096 + p * 256;
            float acc = 0.f;
            #pragma unroll
            for (int k8 = 0; k8 < 8; ++k8) {
                const u32x4 hv = *(const u32x4*)(hb + (ps ^ (k8 << 4)));
                const u32x4 wv = *(const u32x4*)(wp + (k8 << 2));
                #pragma unroll
                for (int dd = 0; dd < 4; ++dd) {
                    acc = __builtin_fmaf(lof(hv[dd]), lof(wv[dd]), acc);
                    acc = __builtin_fmaf(hif(hv[dd]), hif(wv[dd]), acc);
                }
            }
            acc += bias;
            const int mloc = ((p - 1) << 1) + (j >> 1);
            const size_t ob = (size_t)(g0 + g) * 28 + mloc;
            if ((j & 1) == 0) {
                out[ob] = acc;
            } else {
                const float z = acc + BIAS_SP;
                const float sp = (z > 15.f) ? z : __logf(1.f + __expf(z));
                out[(size_t)NB * 28 + ob] = fmaxf(sp, 1e-4f);
            }
        }
    }
}

extern "C" void kernel_launch(void* const* d_in, const int* in_sizes, int n_in,
                              void* d_out, int out_size, void* d_ws, size_t ws_size,
                              hipStream_t stream) {
    (void)in_sizes; (void)n_in; (void)out_size; (void)ws_size;
    const float* x     = (const float*)d_in[0];
    // d_in[1] = edge_index (fixed template, unused), d_in[2] = batch_size
    const float* Wt    = (const float*)d_in[3];
    const float* bt    = (const float*)d_in[4];
    const float* Wl    = (const float*)d_in[5];
    const float* bl    = (const float*)d_in[6];
    const float* Wroot = (const float*)d_in[7];
    const float* Wrel  = (const float*)d_in[8];
    const float* gcb   = (const float*)d_in[9];
    const float* legW  = (const float*)d_in[10];
    const float* legB  = (const float*)d_in[11];
    const float* torW  = (const float*)d_in[12];
    const float* torB  = (const float*)d_in[13];
    unsigned* wsw = (unsigned*)d_ws;           // needs 56320 B of scratch
    setup_kernel<<<14, 256, 0, stream>>>(Wroot, Wrel, legW, torW, wsw);
    leg_main<<<NB / GPB, 256, 0, stream>>>(x, Wt, bt, Wl, bl, gcb, legB, torB, wsw,
                                           (float*)d_out);
}

// Round 7
// 78.734 us; speedup vs baseline: 1.0091x; 1.0091x over previous
//
#include <hip/hip_runtime.h>

#define NB 32768
#define GPB 8
#define THREADS 256
#define BIAS_SP 0.5413248546129181f

typedef __attribute__((ext_vector_type(8))) short bf16x8;
typedef __attribute__((ext_vector_type(4))) float f32x4;
typedef __attribute__((ext_vector_type(4))) unsigned int u32x4;

static __device__ __forceinline__ unsigned f2bfu(float f) {
    union { float f; unsigned u; } v; v.f = f;
    return (v.u + 0x8000u) >> 16;
}
static __device__ __forceinline__ float lof(unsigned u) {
    union { unsigned u; float f; } v; v.u = u << 16; return v.f;
}
static __device__ __forceinline__ float hif(unsigned u) {
    union { unsigned u; float f; } v; v.u = u & 0xFFFF0000u; return v.f;
}
static __device__ __forceinline__ float fast_tanh(float xx) {
    float e = __expf(2.0f * xx);
    return 1.0f - 2.0f * __builtin_amdgcn_rcpf(e + 1.0f);
}
// D[15:0]=bf16(S0), D[31:16]=bf16(S1); RNE. learn_hip m214v22-verified recipe.
#define CVTPK(d, a, b) asm("v_cvt_pk_bf16_f32 %0, %1, %2" : "=v"(d) : "v"(a), "v"(b))

// ---------------------------------------------------------------------------
// Setup: pack into ws (dwords):
//   [0,12288)      conv B-frags (3 layers x 4 ksteps, MFMA lane order)
//   [12288,14080)  head weights (bf16 [item][k])
//   [14080,15104)  encoder B-frag: K-rows = [Wt(8); Wl(4); bt; bl; 0..]
// ---------------------------------------------------------------------------
__global__ void setup_kernel(const float* __restrict__ Wroot, const float* __restrict__ Wrel,
                             const float* __restrict__ legW, const float* __restrict__ torW,
                             const float* __restrict__ Wt, const float* __restrict__ bt,
                             const float* __restrict__ Wl, const float* __restrict__ bl,
                             unsigned* __restrict__ wsw) {
    const int t = blockIdx.x * 256 + threadIdx.x;
    if (t < 3072) {                       // conv B-fragments
        const int i = t >> 10, rem = t & 1023, s = rem >> 8, tt = rem & 255;
        const int lane = tt & 63, ctl = tt >> 6;
        const int bcol = (ctl << 4) + (lane & 15);
        const int kb = ((s & 1) << 5) + ((lane >> 4) << 3);
        const float* M = ((s < 2) ? Wroot : Wrel) + i * 4096 + kb * 64 + bcol;
        u32x4 d;
        #pragma unroll
        for (int dd = 0; dd < 4; ++dd)
            d[dd] = f2bfu(M[(2 * dd) * 64]) | (f2bfu(M[(2 * dd + 1) * 64]) << 16);
        *(u32x4*)(wsw + t * 4) = d;
    } else if (t < 3520) {                // head weights
        const int t2 = t - 3072, item = t2 >> 3, k8 = t2 & 7;
        const int p = (item >> 2) + 1, j = item & 3;
        const int p3 = (p * 11) >> 5;
        const int pm3 = p - p3 * 3;
        const float* src;
        if (pm3 == 0) src = torW + (p3 - 1) * 256 + j;
        else          src = legW + (2 * p3 + pm3 - 1) * 256 + j;
        u32x4 d;
        #pragma unroll
        for (int dd = 0; dd < 4; ++dd) {
            const int k = (k8 << 3) + 2 * dd;
            d[dd] = f2bfu(src[k * 4]) | (f2bfu(src[(k + 1) * 4]) << 16);
        }
        *(u32x4*)(wsw + 12288 + t2 * 4) = d;
    } else if (t < 3776) {                // encoder B-fragment
        const int t3 = t - 3520;
        const int lane = t3 & 63, ctl = t3 >> 6;
        const int col = (ctl << 4) + (lane & 15);
        const int kg = lane >> 4;
        auto encval = [&](int k) -> float {
            if (k < 8)   return Wt[k * 64 + col];
            if (k < 12)  return Wl[(k - 8) * 64 + col];
            if (k == 12) return bt[col];
            if (k == 13) return bl[col];
            return 0.f;
        };
        u32x4 d;
        #pragma unroll
        for (int dd = 0; dd < 4; ++dd) {
            const int k0 = kg * 8 + 2 * dd;
            d[dd] = f2bfu(encval(k0)) | (f2bfu(encval(k0 + 1)) << 16);
        }
        *(u32x4*)(wsw + 14080 + t3 * 4) = d;
    }
}

// ---------------------------------------------------------------------------
// Main: 8 graphs/block, 4 waves. All 4 "layers" (encoder + 3 GraphConv) are
// MFMA: wave = 16-col tile for all 8 graphs. AGG/heads: wave ct owns graphs
// 2ct, 2ct+1 (paired over lane halves).
// LDS/graph: 16 rows x 16 slots(16B) = 4KB; slots 0-7 = h, 8-15 = agg.
// Swizzle: slot_low3 ^= (row & 7).
// ---------------------------------------------------------------------------
__global__ __launch_bounds__(THREADS, 4) void leg_main(
    const float* __restrict__ x,
    const float* __restrict__ gcb,
    const float* __restrict__ legB, const float* __restrict__ torB,
    const unsigned* __restrict__ wsw,
    float* __restrict__ out)
{
    __shared__ __align__(16) unsigned char smem[GPB * 4096];
    const int tid  = threadIdx.x;
    const int lane = tid & 63;
    const int ct   = tid >> 6;
    const int g0   = blockIdx.x * GPB;

    const int bcol = (ct << 4) + (lane & 15);
    const float cb0 = gcb[bcol], cb1 = gcb[64 + bcol], cb2 = gcb[128 + bcol];

    // --- per-lane LDS byte offsets (conv) ---
    const int row = lane & 15, kg = lane >> 4;
    const int row3 = (row * 11) >> 5;
    const int tors = row3 * 3;
    const int isT  = (row == tors);
    const int rowR = isT ? row : tors;          // leg rows read torso h as agg
    const int voffA0  = row * 256 + (((kg ^ row) & 7) << 4);
    const int voffA1  = voffA0 ^ 0x40;
    const int voffA2  = rowR * 256 + (((kg ^ rowR) & 7) << 4) + (isT ? 128 : 0);
    const int voffA3  = voffA2 ^ 0x40;
    int voffC[4];
    #pragma unroll
    for (int r = 0; r < 4; ++r) {
        const int rr = (kg << 2) + r;
        voffC[r] = rr * 256 + (((((ct << 1) + ((lane >> 3) & 1)) ^ rr) & 7) << 4) + ((lane & 7) << 1);
    }

    // --- paired-AGG mapping: lanes<32 -> graph 2ct, >=32 -> 2ct+1 ---
    const int c2 = lane & 31;
    unsigned char* gbase = smem + ((ct << 1) + (lane >> 5)) * 4096;
    const int aoff = (c2 & 3) << 2;
    int agg_ra[15];
    #pragma unroll
    for (int r = 0; r < 15; ++r)
        agg_ra[r] = r * 256 + ((((c2 >> 2) ^ r) & 7) << 4) + aoff;
    int agg_wa[5];
    #pragma unroll
    for (int i = 0; i < 5; ++i) {
        const int r = 3 * i;
        agg_wa[i] = r * 256 + 128 + ((((c2 >> 2) ^ r) & 7) << 4) + aoff;
    }
#define RD32(r)  (*(const unsigned*)(gbase + agg_ra[r]))
#define WR32(i, flo, fhi) do { unsigned _w; CVTPK(_w, flo, fhi); \
    *(unsigned*)(gbase + agg_wa[i]) = _w; } while (0)
#define AGG() do { \
    unsigned u[15]; \
    _Pragma("unroll") for (int r = 0; r < 15; ++r) u[r] = RD32(r); \
    float l3 = lof(u[3]), h3 = hif(u[3]), l6 = lof(u[6]), h6 = hif(u[6]), l9 = lof(u[9]), h9 = hif(u[9]); \
    WR32(0,  lof(u[1]) + lof(u[2]) + l3,              hif(u[1]) + hif(u[2]) + h3); \
    WR32(1,  lof(u[4]) + lof(u[5]) + lof(u[0]) + l6,  hif(u[4]) + hif(u[5]) + hif(u[0]) + h6); \
    WR32(2,  lof(u[7]) + lof(u[8]) + l3 + l9,         hif(u[7]) + hif(u[8]) + h3 + h9); \
    WR32(3,  lof(u[10]) + lof(u[11]) + l6 + lof(u[12]), hif(u[10]) + hif(u[11]) + h6 + hif(u[12])); \
    WR32(4,  lof(u[13]) + lof(u[14]) + l9,            hif(u[13]) + hif(u[14]) + h9); \
} while (0)
// epilogue: tanh(acc) -> bf16 -> LDS h (shared by all 4 layers)
#define EPI() do { \
    _Pragma("unroll") for (int g = 0; g < GPB; ++g) { \
        _Pragma("unroll") for (int r = 0; r < 4; ++r) { \
            const float tv = fast_tanh(acc[g][r]); \
            unsigned uu; CVTPK(uu, tv, tv); \
            *(unsigned short*)(smem + g * 4096 + voffC[r]) = (unsigned short)uu; \
        } } } while (0)

    // --- encoder (layer 0) as MFMA: A = [isT*x(8) | isL*x(0:4) | isT | isL] ---
    const unsigned mT = (isT && row < 15) ? 0xFFFFFFFFu : 0u;
    const unsigned mL = isT ? 0u : 0xFFFFFFFFu;
    const unsigned m01 = (kg == 0) ? mT : ((kg == 1) ? mL : 0u);
    const unsigned m45 = (kg == 0) ? mT : 0u;
    const unsigned c1213 = (kg == 1) ? ((mT ? 0x3F80u : 0u) | (mL ? 0x3F800000u : 0u)) : 0u;
    const int rowc = (row < 15) ? row : 0;
    const bf16x8 bfrE = *(const bf16x8*)(wsw + 14080 + tid * 4);

    f32x4 acc[GPB];
    #pragma unroll
    for (int g = 0; g < GPB; ++g) {
        const float4* xr = (const float4*)x + ((size_t)(g0 + g) * 15 + rowc) * 2;
        const float4 x0 = xr[0], x1 = xr[1];
        unsigned a01, a23, a45, a67;
        CVTPK(a01, x0.x, x0.y); CVTPK(a23, x0.z, x0.w);
        CVTPK(a45, x1.x, x1.y); CVTPK(a67, x1.z, x1.w);
        union { u32x4 u; bf16x8 b; } af;
        af.u[0] = a01 & m01;
        af.u[1] = a23 & m01;
        af.u[2] = (a45 & m45) | c1213;   // kg1: bias indicators; kg0: x[4:6]
        af.u[3] = a67 & m45;
        const f32x4 z = { 0.f, 0.f, 0.f, 0.f };   // bias folded into K
        acc[g] = __builtin_amdgcn_mfma_f32_16x16x32_bf16(af.b, bfrE, z, 0, 0, 0);
    }
    EPI();                   // waves write disjoint col-tiles -> no barrier before
    __syncthreads();
    AGG();
    __syncthreads();

    // --- 3x GraphConv via MFMA ---
    #pragma unroll
    for (int it = 0; it < 3; ++it) {
        bf16x8 bfr[4];
        #pragma unroll
        for (int s = 0; s < 4; ++s)
            bfr[s] = *(const bf16x8*)(wsw + ((it * 4 + s) * 256 + tid) * 4);
        const float cbi = (it == 0) ? cb0 : (it == 1) ? cb1 : cb2;
        #pragma unroll
        for (int g = 0; g < GPB; ++g) {
            const unsigned char* sg = smem + g * 4096;
            const bf16x8 a0 = *(const bf16x8*)(sg + voffA0);
            const bf16x8 a1 = *(const bf16x8*)(sg + voffA1);
            const bf16x8 a2 = *(const bf16x8*)(sg + voffA2);
            const bf16x8 a3 = *(const bf16x8*)(sg + voffA3);
            f32x4 c = { cbi, cbi, cbi, cbi };
            c = __builtin_amdgcn_mfma_f32_16x16x32_bf16(a0, bfr[0], c, 0, 0, 0);
            c = __builtin_amdgcn_mfma_f32_16x16x32_bf16(a1, bfr[1], c, 0, 0, 0);
            c = __builtin_amdgcn_mfma_f32_16x16x32_bf16(a2, bfr[2], c, 0, 0, 0);
            c = __builtin_amdgcn_mfma_f32_16x16x32_bf16(a3, bfr[3], c, 0, 0, 0);
            acc[g] = c;
        }
        __syncthreads();     // all A reads done before overwriting h
        EPI();
        __syncthreads();
        if (it < 2) { AGG(); __syncthreads(); }
    }

    // --- heads: wave ct -> graphs 2ct, 2ct+1; lane = (p,j) item ---
    // unpack-FMA path (proven). Raw-asm v_dot2_f32_bf16 gave a deterministic
    // 4.7e-2 error - do not reintroduce via raw asm.
    if (lane < 56) {
        const int p = (lane >> 2) + 1, j = lane & 3;
        const int p3 = (p * 11) >> 5;
        const int pm3 = p - p3 * 3;
        float bias;
        if (pm3 == 0) bias = torB[((p3 - 1) << 2) + j];
        else          bias = legB[(((p3 << 1) + pm3 - 1) << 2) + j];
        const unsigned* wp = wsw + 12288 + (lane << 5);
        const int ps = (p & 7) << 4;
        #pragma unroll
        for (int gs = 0; gs < 2; ++gs) {
            const int g = (ct << 1) + gs;
            const unsigned char* hb = smem + g * 4096 + p * 256;
            float acch = 0.f;
            #pragma unroll
            for (int k8 = 0; k8 < 8; ++k8) {
                const u32x4 hv = *(const u32x4*)(hb + (ps ^ (k8 << 4)));
                const u32x4 wv = *(const u32x4*)(wp + (k8 << 2));
                #pragma unroll
                for (int dd = 0; dd < 4; ++dd) {
                    acch = __builtin_fmaf(lof(hv[dd]), lof(wv[dd]), acch);
                    acch = __builtin_fmaf(hif(hv[dd]), hif(wv[dd]), acch);
                }
            }
            acch += bias;
            const int mloc = ((p - 1) << 1) + (j >> 1);
            const size_t ob = (size_t)(g0 + g) * 28 + mloc;
            if ((j & 1) == 0) {
                out[ob] = acch;
            } else {
                const float z = acch + BIAS_SP;
                const float sp = (z > 15.f) ? z : __logf(1.f + __expf(z));
                out[(size_t)NB * 28 + ob] = fmaxf(sp, 1e-4f);
            }
        }
    }
}

extern "C" void kernel_launch(void* const* d_in, const int* in_sizes, int n_in,
                              void* d_out, int out_size, void* d_ws, size_t ws_size,
                              hipStream_t stream) {
    (void)in_sizes; (void)n_in; (void)out_size; (void)ws_size;
    const float* x     = (const float*)d_in[0];
    // d_in[1] = edge_index (fixed template, unused), d_in[2] = batch_size
    const float* Wt    = (const float*)d_in[3];
    const float* bt    = (const float*)d_in[4];
    const float* Wl    = (const float*)d_in[5];
    const float* bl    = (const float*)d_in[6];
    const float* Wroot = (const float*)d_in[7];
    const float* Wrel  = (const float*)d_in[8];
    const float* gcb   = (const float*)d_in[9];
    const float* legW  = (const float*)d_in[10];
    const float* legB  = (const float*)d_in[11];
    const float* torW  = (const float*)d_in[12];
    const float* torB  = (const float*)d_in[13];
    unsigned* wsw = (unsigned*)d_ws;           // needs 60416 B of scratch
    setup_kernel<<<15, 256, 0, stream>>>(Wroot, Wrel, legW, torW, Wt, bt, Wl, bl, wsw);
    leg_main<<<NB / GPB, 256, 0, stream>>>(x, gcb, legB, torB, wsw, (float*)d_out);
}